// Round 1
// baseline (849.275 us; speedup 1.0000x reference)
//
#include <hip/hip_runtime.h>
#include <stdint.h>
#include <math.h>

#define IN_DIM 512
#define HID    256
#define OUTD   128
#define LN_EPS 1e-5f

typedef unsigned short u16;
typedef unsigned int   u32;
typedef short short8 __attribute__((ext_vector_type(8)));
typedef float f32x4  __attribute__((ext_vector_type(4)));

__device__ __forceinline__ float bf2f(u32 h) {
  union { u32 u; float f; } c; c.u = h << 16; return c.f;
}
__device__ __forceinline__ u16 f2bf(float f) {
  union { float f; u32 u; } c; c.f = f;
  u32 u = c.u;
  return (u16)((u + 0x7FFFu + ((u >> 16) & 1u)) >> 16);  // RNE
}

// ---------------- prep kernels ----------------
__global__ void k_cvt_f32_bf16_v4(const float* __restrict__ in, u16* __restrict__ out, int n4) {
  int i = blockIdx.x * blockDim.x + threadIdx.x;
  if (i >= n4) return;
  const float4 v = ((const float4*)in)[i];
  ushort4 o;
  o.x = f2bf(v.x); o.y = f2bf(v.y); o.z = f2bf(v.z); o.w = f2bf(v.w);
  ((ushort4*)out)[i] = o;
}

// in: [K][Nw] fp32 row-major, out: [Nw][K] bf16 row-major
__global__ void k_transpose_w(const float* __restrict__ in, u16* __restrict__ out, int K, int Nw) {
  int idx = blockIdx.x * blockDim.x + threadIdx.x;
  if (idx >= K * Nw) return;
  int n = idx / K, k = idx - n * K;
  out[idx] = f2bf(in[(size_t)k * Nw + n]);
}

__global__ void k_concat4(const float* __restrict__ b0, const float* __restrict__ b1,
                          const float* __restrict__ b2, const float* __restrict__ b3,
                          float* __restrict__ out, int H) {
  int i = blockIdx.x * blockDim.x + threadIdx.x;
  if (i >= 4 * H) return;
  const float* s = (i < H) ? b0 : (i < 2 * H) ? b1 : (i < 3 * H) ? b2 : b3;
  out[i] = s[i & (H - 1)];
}

// ---------------- edge sort (counting sort by dst) ----------------
__global__ void k_hist(const int* __restrict__ dst, int* __restrict__ deg, int E) {
  int e = blockIdx.x * blockDim.x + threadIdx.x;
  if (e < E) atomicAdd(&deg[dst[e]], 1);
}

__global__ void k_block_sum(const int* __restrict__ deg, int* __restrict__ bsum, int n) {
  __shared__ int sm[256];
  int i = blockIdx.x * 256 + threadIdx.x;
  sm[threadIdx.x] = (i < n) ? deg[i] : 0;
  __syncthreads();
  for (int off = 128; off > 0; off >>= 1) {
    if (threadIdx.x < off) sm[threadIdx.x] += sm[threadIdx.x + off];
    __syncthreads();
  }
  if (threadIdx.x == 0) bsum[blockIdx.x] = sm[0];
}

__global__ void k_scan_bsum(const int* __restrict__ bsum, int* __restrict__ boff, int nb) {
  __shared__ int sm[256];
  int t = threadIdx.x;
  int v = (t < nb) ? bsum[t] : 0;
  sm[t] = v;
  __syncthreads();
  for (int off = 1; off < 256; off <<= 1) {
    int tmp = (t >= off) ? sm[t - off] : 0;
    __syncthreads();
    sm[t] += tmp;
    __syncthreads();
  }
  if (t < nb) boff[t] = sm[t] - v;  // exclusive
}

__global__ void k_scan_final(const int* __restrict__ deg, const int* __restrict__ boff,
                             int* __restrict__ offsets, int n, int total) {
  __shared__ int sm[256];
  int t = threadIdx.x;
  int i = blockIdx.x * 256 + t;
  int v = (i < n) ? deg[i] : 0;
  sm[t] = v;
  __syncthreads();
  for (int off = 1; off < 256; off <<= 1) {
    int tmp = (t >= off) ? sm[t - off] : 0;
    __syncthreads();
    sm[t] += tmp;
    __syncthreads();
  }
  if (i < n) offsets[i] = boff[blockIdx.x] + sm[t] - v;
  if (i == 0) offsets[n] = total;
}

__global__ void k_copy_int(const int* __restrict__ in, int* __restrict__ out, int n) {
  int i = blockIdx.x * blockDim.x + threadIdx.x;
  if (i < n) out[i] = in[i];
}

__global__ void k_scatter(const int* __restrict__ src, const int* __restrict__ dst,
                          int* __restrict__ cursor, int* __restrict__ ssrc, int E) {
  int e = blockIdx.x * blockDim.x + threadIdx.x;
  if (e >= E) return;
  int d = dst[e];
  int pos = atomicAdd(&cursor[d], 1);
  ssrc[pos] = src[e];
}

// ---------------- bf16 NT GEMM: C[M][Nt] = A[M][K] * Bt[Nt][K]^T + bias ----------------
// 128x128 tile, 256 threads (4 waves, 2x2 of 64x64 per wave), mfma 16x16x32 bf16.
__global__ __launch_bounds__(256) void k_gemm_bf16_nt(
    const u16* __restrict__ A, const u16* __restrict__ Bt, const float* __restrict__ bias,
    u16* __restrict__ C, int M, int K, int Nt) {
  __shared__ __align__(16) u16 As[128 * 40];  // +8 pad breaks LDS bank aliasing
  __shared__ __align__(16) u16 Bs[128 * 40];
  const int tid = threadIdx.x;
  const int bm0 = blockIdx.x * 128;
  const int bn0 = blockIdx.y * 128;
  const int wave = tid >> 6, lane = tid & 63;
  const int q = lane >> 4, r16 = lane & 15;
  const int wm = (wave >> 1) * 64, wn = (wave & 1) * 64;

  f32x4 acc[4][4];
#pragma unroll
  for (int i = 0; i < 4; i++)
#pragma unroll
    for (int j = 0; j < 4; j++) acc[i][j] = (f32x4){0.f, 0.f, 0.f, 0.f};

  const int row0 = tid >> 2;  // 0..63
  const int kg = tid & 3;     // 16B chunk within the 32-wide k slab

  for (int kt = 0; kt < K; kt += 32) {
#pragma unroll
    for (int h = 0; h < 2; ++h) {
      int row = row0 + h * 64;
      int ga = bm0 + row;
      uint4 av = {0u, 0u, 0u, 0u};
      if (ga < M) av = *(const uint4*)(A + (size_t)ga * K + kt + kg * 8);
      *(uint4*)(&As[row * 40 + kg * 8]) = av;
      int gb = bn0 + row;  // Nt is a multiple of 128 -> always in range
      uint4 bv = *(const uint4*)(Bt + (size_t)gb * K + kt + kg * 8);
      *(uint4*)(&Bs[row * 40 + kg * 8]) = bv;
    }
    __syncthreads();
    short8 af[4], bfr[4];
#pragma unroll
    for (int i = 0; i < 4; i++) af[i] = *(const short8*)(&As[(wm + i * 16 + r16) * 40 + q * 8]);
#pragma unroll
    for (int j = 0; j < 4; j++) bfr[j] = *(const short8*)(&Bs[(wn + j * 16 + r16) * 40 + q * 8]);
#pragma unroll
    for (int i = 0; i < 4; i++)
#pragma unroll
      for (int j = 0; j < 4; j++)
        acc[i][j] = __builtin_amdgcn_mfma_f32_16x16x32_bf16(af[i], bfr[j], acc[i][j], 0, 0, 0);
    __syncthreads();
  }

#pragma unroll
  for (int i = 0; i < 4; i++) {
#pragma unroll
    for (int r = 0; r < 4; r++) {
      int grow = bm0 + wm + i * 16 + q * 4 + r;  // C/D: row = quad*4 + reg
      if (grow >= M) continue;
      size_t rbase = (size_t)grow * Nt;
#pragma unroll
      for (int j = 0; j < 4; j++) {
        int gcol = bn0 + wn + j * 16 + r16;  // C/D: col = lane&15
        float v = acc[i][j][r] + bias[gcol];
        C[rbase + gcol] = f2bf(v);
      }
    }
  }
}

// ---------------- per-dst online-softmax aggregation ----------------
template <int VPL>
__device__ __forceinline__ void load_bf(const u16* __restrict__ p, int lane, float* f) {
  if constexpr (VPL == 4) {
    uint2 r = *(const uint2*)(p + lane * 4);
    f[0] = bf2f(r.x & 0xffffu); f[1] = bf2f(r.x >> 16);
    f[2] = bf2f(r.y & 0xffffu); f[3] = bf2f(r.y >> 16);
  } else {
    u32 r = *(const u32*)(p + lane * 2);
    f[0] = bf2f(r & 0xffffu); f[1] = bf2f(r >> 16);
  }
}

template <int H, bool OUT_BF16>
__global__ void k_conv(const u16* __restrict__ qkvs, const int* __restrict__ offsets,
                       const int* __restrict__ ssrc, u16* __restrict__ out_bf,
                       float* __restrict__ out_f, int n, float scale) {
  constexpr int VPL = H / 64;
  int gw = (blockIdx.x * blockDim.x + threadIdx.x) >> 6;  // one wave per dst node
  int lane = threadIdx.x & 63;
  if (gw >= n) return;
  const u16* base = qkvs + (size_t)gw * (4 * H);
  float qf[VPL];
  load_bf<VPL>(base, lane, qf);
  int beg = offsets[gw], end = offsets[gw + 1];
  float m = -INFINITY, l = 0.f;
  float agg[VPL];
#pragma unroll
  for (int w = 0; w < VPL; w++) agg[w] = 0.f;
  for (int i = beg; i < end; ++i) {
    int s = ssrc[i];
    const u16* kb = qkvs + (size_t)s * (4 * H) + H;
    float kf[VPL];
    load_bf<VPL>(kb, lane, kf);
    float d = 0.f;
#pragma unroll
    for (int w = 0; w < VPL; w++) d += qf[w] * kf[w];
#pragma unroll
    for (int off = 32; off > 0; off >>= 1) d += __shfl_xor(d, off, 64);
    float score = d * scale;
    float nm = fmaxf(m, score);
    float sc = __expf(m - nm);  // m = -inf on first edge -> 0
    float p = __expf(score - nm);
    m = nm;
    l = l * sc + p;
    float vf[VPL];
    load_bf<VPL>(kb + H, lane, vf);
#pragma unroll
    for (int w = 0; w < VPL; w++) agg[w] = agg[w] * sc + p * vf[w];
  }
  float sf[VPL];
  load_bf<VPL>(base + 3 * H, lane, sf);
  float inv = (end > beg) ? 1.f / l : 0.f;
#pragma unroll
  for (int w = 0; w < VPL; w++) {
    float r = agg[w] * inv + sf[w];
    if (OUT_BF16) out_bf[(size_t)gw * H + lane * VPL + w] = f2bf(r);
    else out_f[(size_t)gw * H + lane * VPL + w] = r;
  }
}

// ---------------- graph layernorm (global mean/std) ----------------
__global__ void k_stats_bf16(const u16* __restrict__ a, int n, double* __restrict__ st) {
  float s = 0.f, s2 = 0.f;
  for (int i = blockIdx.x * blockDim.x + threadIdx.x; i < n; i += gridDim.x * blockDim.x) {
    float v = bf2f(a[i]);
    s += v; s2 += v * v;
  }
  __shared__ float sm[256], sm2[256];
  sm[threadIdx.x] = s; sm2[threadIdx.x] = s2;
  __syncthreads();
  for (int off = 128; off > 0; off >>= 1) {
    if (threadIdx.x < off) { sm[threadIdx.x] += sm[threadIdx.x + off]; sm2[threadIdx.x] += sm2[threadIdx.x + off]; }
    __syncthreads();
  }
  if (threadIdx.x == 0) { atomicAdd(&st[0], (double)sm[0]); atomicAdd(&st[1], (double)sm2[0]); }
}

__global__ void k_stats_f32(const float* __restrict__ a, int n, double* __restrict__ st) {
  float s = 0.f, s2 = 0.f;
  for (int i = blockIdx.x * blockDim.x + threadIdx.x; i < n; i += gridDim.x * blockDim.x) {
    float v = a[i];
    s += v; s2 += v * v;
  }
  __shared__ float sm[256], sm2[256];
  sm[threadIdx.x] = s; sm2[threadIdx.x] = s2;
  __syncthreads();
  for (int off = 128; off > 0; off >>= 1) {
    if (threadIdx.x < off) { sm[threadIdx.x] += sm[threadIdx.x + off]; sm2[threadIdx.x] += sm2[threadIdx.x + off]; }
    __syncthreads();
  }
  if (threadIdx.x == 0) { atomicAdd(&st[0], (double)sm[0]); atomicAdd(&st[1], (double)sm2[0]); }
}

__global__ void k_finstats(const double* __restrict__ st, float* __restrict__ fs, double cnt) {
  double mu = st[0] / cnt;
  double var = st[1] / cnt - mu * mu;
  if (var < 0.0) var = 0.0;
  fs[0] = (float)mu;
  fs[1] = (float)(1.0 / (sqrt(var) + (double)LN_EPS));
}

__global__ void k_norm_elu_bf16(const u16* __restrict__ a, const float* __restrict__ g,
                                const float* __restrict__ b, const float* __restrict__ fs,
                                u16* __restrict__ out, int n, int Hmask) {
  int i = blockIdx.x * blockDim.x + threadIdx.x;
  if (i >= n) return;
  int c = i & Hmask;
  float y = (bf2f(a[i]) - fs[0]) * fs[1] * g[c] + b[c];
  y = (y > 0.f) ? y : (__expf(y) - 1.f);  // ELU(alpha=1)
  out[i] = f2bf(y);
}

__global__ void k_norm_f32(float* __restrict__ a, const float* __restrict__ g,
                           const float* __restrict__ b, const float* __restrict__ fs,
                           int n, int Hmask) {
  int i = blockIdx.x * blockDim.x + threadIdx.x;
  if (i >= n) return;
  int c = i & Hmask;
  a[i] = (a[i] - fs[0]) * fs[1] * g[c] + b[c];
}

// ---------------- launch ----------------
extern "C" void kernel_launch(void* const* d_in, const int* in_sizes, int n_in,
                              void* d_out, int out_size, void* d_ws, size_t ws_size,
                              hipStream_t stream) {
  const float* x   = (const float*)d_in[0];
  const float* Wq1 = (const float*)d_in[1];  const float* bq1 = (const float*)d_in[2];
  const float* Wk1 = (const float*)d_in[3];  const float* bk1 = (const float*)d_in[4];
  const float* Wv1 = (const float*)d_in[5];  const float* bv1 = (const float*)d_in[6];
  const float* Ws1 = (const float*)d_in[7];  const float* bs1 = (const float*)d_in[8];
  const float* g1  = (const float*)d_in[9];  const float* be1 = (const float*)d_in[10];
  const float* Wq2 = (const float*)d_in[11]; const float* bq2 = (const float*)d_in[12];
  const float* Wk2 = (const float*)d_in[13]; const float* bk2 = (const float*)d_in[14];
  const float* Wv2 = (const float*)d_in[15]; const float* bv2 = (const float*)d_in[16];
  const float* Ws2 = (const float*)d_in[17]; const float* bs2 = (const float*)d_in[18];
  const float* g2  = (const float*)d_in[19]; const float* be2 = (const float*)d_in[20];
  const int*   ei  = (const int*)d_in[21];

  const int N = in_sizes[0] / IN_DIM;   // 50000
  const int E = in_sizes[21] / 2;       // 800000
  const int* esrc = ei;
  const int* edst = ei + E;

  // ---- workspace carve (256B aligned) ----
  char* w = (char*)d_ws;
  auto carve = [&](size_t bytes) { char* p = w; w += (bytes + 255) & ~(size_t)255; return p; };
  u16* x_bf  = (u16*)carve((size_t)N * IN_DIM * 2);          // later reused as h1
  u16* Wt1   = (u16*)carve((size_t)4 * HID * IN_DIM * 2);
  u16* Wt2   = (u16*)carve((size_t)4 * OUTD * HID * 2);
  float* bc1 = (float*)carve(4 * HID * 4);
  float* bc2 = (float*)carve(4 * OUTD * 4);
  u16* qkvs1 = (u16*)carve((size_t)N * 4 * HID * 2);         // later reused as qkvs2
  u16* a1    = (u16*)carve((size_t)N * HID * 2);
  int* deg   = (int*)carve((size_t)(N + 1) * 4);
  int* offs  = (int*)carve((size_t)(N + 1) * 4);
  int* cur   = (int*)carve((size_t)(N + 1) * 4);
  int* ssrc  = (int*)carve((size_t)E * 4);
  int* bsum  = (int*)carve(1024);
  int* boff  = (int*)carve(1024);
  double* st = (double*)carve(64);   // st[0..1]: layer1, st[2..3]: layer2
  float* fs  = (float*)carve(64);    // fs[0..1], fs[2..3]
  u16* h1    = x_bf;                 // x_bf dead after GEMM1
  u16* qkvs2 = qkvs1;                // qkvs1 dead after conv1

  hipMemsetAsync(deg, 0, (size_t)N * 4, stream);
  hipMemsetAsync(st, 0, 64, stream);

  // ---- prep ----
  int n4 = N * IN_DIM / 4;
  k_cvt_f32_bf16_v4<<<(n4 + 255) / 256, 256, 0, stream>>>(x, x_bf, n4);
  k_transpose_w<<<(IN_DIM * HID + 255) / 256, 256, 0, stream>>>(Wq1, Wt1 + 0 * (size_t)HID * IN_DIM, IN_DIM, HID);
  k_transpose_w<<<(IN_DIM * HID + 255) / 256, 256, 0, stream>>>(Wk1, Wt1 + 1 * (size_t)HID * IN_DIM, IN_DIM, HID);
  k_transpose_w<<<(IN_DIM * HID + 255) / 256, 256, 0, stream>>>(Wv1, Wt1 + 2 * (size_t)HID * IN_DIM, IN_DIM, HID);
  k_transpose_w<<<(IN_DIM * HID + 255) / 256, 256, 0, stream>>>(Ws1, Wt1 + 3 * (size_t)HID * IN_DIM, IN_DIM, HID);
  k_concat4<<<(4 * HID + 255) / 256, 256, 0, stream>>>(bq1, bk1, bv1, bs1, bc1, HID);
  k_transpose_w<<<(HID * OUTD + 255) / 256, 256, 0, stream>>>(Wq2, Wt2 + 0 * (size_t)OUTD * HID, HID, OUTD);
  k_transpose_w<<<(HID * OUTD + 255) / 256, 256, 0, stream>>>(Wk2, Wt2 + 1 * (size_t)OUTD * HID, HID, OUTD);
  k_transpose_w<<<(HID * OUTD + 255) / 256, 256, 0, stream>>>(Wv2, Wt2 + 2 * (size_t)OUTD * HID, HID, OUTD);
  k_transpose_w<<<(HID * OUTD + 255) / 256, 256, 0, stream>>>(Ws2, Wt2 + 3 * (size_t)OUTD * HID, HID, OUTD);
  k_concat4<<<(4 * OUTD + 255) / 256, 256, 0, stream>>>(bq2, bk2, bv2, bs2, bc2, OUTD);

  // ---- counting sort of edges by dst ----
  int nb = (N + 255) / 256;
  k_hist<<<(E + 255) / 256, 256, 0, stream>>>(edst, deg, E);
  k_block_sum<<<nb, 256, 0, stream>>>(deg, bsum, N);
  k_scan_bsum<<<1, 256, 0, stream>>>(bsum, boff, nb);
  k_scan_final<<<nb, 256, 0, stream>>>(deg, boff, offs, N, E);
  k_copy_int<<<nb, 256, 0, stream>>>(offs, cur, N);
  k_scatter<<<(E + 255) / 256, 256, 0, stream>>>(esrc, edst, cur, ssrc, E);

  // ---- layer 1 ----
  dim3 gg1((N + 127) / 128, (4 * HID) / 128);
  k_gemm_bf16_nt<<<gg1, 256, 0, stream>>>(x_bf, Wt1, bc1, qkvs1, N, IN_DIM, 4 * HID);
  k_conv<HID, true><<<(N + 3) / 4, 256, 0, stream>>>(qkvs1, offs, ssrc, a1, nullptr, N,
                                                     1.0f / sqrtf((float)HID));
  k_stats_bf16<<<2048, 256, 0, stream>>>(a1, N * HID, st);
  k_finstats<<<1, 1, 0, stream>>>(st, fs, (double)N * HID);
  k_norm_elu_bf16<<<(N * HID + 255) / 256, 256, 0, stream>>>(a1, g1, be1, fs, h1, N * HID, HID - 1);

  // ---- layer 2 ----
  dim3 gg2((N + 127) / 128, (4 * OUTD) / 128);
  k_gemm_bf16_nt<<<gg2, 256, 0, stream>>>(h1, Wt2, bc2, qkvs2, N, HID, 4 * OUTD);
  k_conv<OUTD, false><<<(N + 3) / 4, 256, 0, stream>>>(qkvs2, offs, ssrc, nullptr, (float*)d_out, N,
                                                       1.0f / sqrtf((float)OUTD));
  k_stats_f32<<<2048, 256, 0, stream>>>((const float*)d_out, N * OUTD, st + 2);
  k_finstats<<<1, 1, 0, stream>>>(st + 2, fs + 2, (double)N * OUTD);
  k_norm_f32<<<(N * OUTD + 255) / 256, 256, 0, stream>>>((float*)d_out, g2, be2, fs + 2, N * OUTD, OUTD - 1);
}

// Round 2
// 772.238 us; speedup vs baseline: 1.0998x; 1.0998x over previous
//
#include <hip/hip_runtime.h>
#include <stdint.h>
#include <math.h>

#define IN_DIM 512
#define HID    256
#define OUTD   128
#define LN_EPS 1e-5f

typedef unsigned short u16;
typedef unsigned int   u32;
typedef short short8 __attribute__((ext_vector_type(8)));
typedef float f32x4  __attribute__((ext_vector_type(4)));

__device__ __forceinline__ float bf2f(u32 h) {
  union { u32 u; float f; } c; c.u = h << 16; return c.f;
}
__device__ __forceinline__ u16 f2bf(float f) {
  union { float f; u32 u; } c; c.f = f;
  u32 u = c.u;
  return (u16)((u + 0x7FFFu + ((u >> 16) & 1u)) >> 16);  // RNE
}

__device__ __forceinline__ void gload_lds16(const void* g, void* l) {
  __builtin_amdgcn_global_load_lds((const __attribute__((address_space(1))) void*)g,
                                   (__attribute__((address_space(3))) void*)l, 16, 0, 0);
}

// ---------------- prep kernels ----------------
__global__ void k_cvt_f32_bf16_v4(const float* __restrict__ in, u16* __restrict__ out, int n4) {
  int i = blockIdx.x * blockDim.x + threadIdx.x;
  if (i >= n4) return;
  const float4 v = ((const float4*)in)[i];
  ushort4 o;
  o.x = f2bf(v.x); o.y = f2bf(v.y); o.z = f2bf(v.z); o.w = f2bf(v.w);
  ((ushort4*)out)[i] = o;
}

// in: [K][Nw] fp32 row-major, out: [Nw][K] bf16 row-major
__global__ void k_transpose_w(const float* __restrict__ in, u16* __restrict__ out, int K, int Nw) {
  int idx = blockIdx.x * blockDim.x + threadIdx.x;
  if (idx >= K * Nw) return;
  int n = idx / K, k = idx - n * K;
  out[idx] = f2bf(in[(size_t)k * Nw + n]);
}

__global__ void k_concat4(const float* __restrict__ b0, const float* __restrict__ b1,
                          const float* __restrict__ b2, const float* __restrict__ b3,
                          float* __restrict__ out, int H) {
  int i = blockIdx.x * blockDim.x + threadIdx.x;
  if (i >= 4 * H) return;
  const float* s = (i < H) ? b0 : (i < 2 * H) ? b1 : (i < 3 * H) ? b2 : b3;
  out[i] = s[i & (H - 1)];
}

// ---------------- edge sort (counting sort by dst) ----------------
__global__ void k_hist(const int* __restrict__ dst, int* __restrict__ deg, int E) {
  int e = blockIdx.x * blockDim.x + threadIdx.x;
  if (e < E) atomicAdd(&deg[dst[e]], 1);
}

__global__ void k_block_sum(const int* __restrict__ deg, int* __restrict__ bsum, int n) {
  __shared__ int sm[256];
  int i = blockIdx.x * 256 + threadIdx.x;
  sm[threadIdx.x] = (i < n) ? deg[i] : 0;
  __syncthreads();
  for (int off = 128; off > 0; off >>= 1) {
    if (threadIdx.x < off) sm[threadIdx.x] += sm[threadIdx.x + off];
    __syncthreads();
  }
  if (threadIdx.x == 0) bsum[blockIdx.x] = sm[0];
}

__global__ void k_scan_bsum(const int* __restrict__ bsum, int* __restrict__ boff, int nb) {
  __shared__ int sm[256];
  int t = threadIdx.x;
  int v = (t < nb) ? bsum[t] : 0;
  sm[t] = v;
  __syncthreads();
  for (int off = 1; off < 256; off <<= 1) {
    int tmp = (t >= off) ? sm[t - off] : 0;
    __syncthreads();
    sm[t] += tmp;
    __syncthreads();
  }
  if (t < nb) boff[t] = sm[t] - v;  // exclusive
}

__global__ void k_scan_final(const int* __restrict__ deg, const int* __restrict__ boff,
                             int* __restrict__ offsets, int n, int total) {
  __shared__ int sm[256];
  int t = threadIdx.x;
  int i = blockIdx.x * 256 + t;
  int v = (i < n) ? deg[i] : 0;
  sm[t] = v;
  __syncthreads();
  for (int off = 1; off < 256; off <<= 1) {
    int tmp = (t >= off) ? sm[t - off] : 0;
    __syncthreads();
    sm[t] += tmp;
    __syncthreads();
  }
  if (i < n) offsets[i] = boff[blockIdx.x] + sm[t] - v;
  if (i == 0) offsets[n] = total;
}

__global__ void k_copy_int(const int* __restrict__ in, int* __restrict__ out, int n) {
  int i = blockIdx.x * blockDim.x + threadIdx.x;
  if (i < n) out[i] = in[i];
}

__global__ void k_scatter(const int* __restrict__ src, const int* __restrict__ dst,
                          int* __restrict__ cursor, int* __restrict__ ssrc, int E) {
  int e = blockIdx.x * blockDim.x + threadIdx.x;
  if (e >= E) return;
  int d = dst[e];
  int pos = atomicAdd(&cursor[d], 1);
  ssrc[pos] = src[e];
}

// ---------------- bf16 NT GEMM (m97 structure): C[M][Nt] = A[M][K]*Bt[Nt][K]^T + bias ----
// 128x128 tile, 256 threads (4 waves, 2x2 of 64x64 per wave), mfma 16x16x32 bf16.
// Staging via global_load_lds width=16 into UNPADDED stride-32 LDS (DMA is
// wave-uniform-base + lane*16; padding is illegal). Bank conflicts on the
// ds_read_b128 fragment reads are accepted per m97/m98.
__global__ __launch_bounds__(256) void k_gemm_bf16_nt(
    const u16* __restrict__ A, const u16* __restrict__ Bt, const float* __restrict__ bias,
    u16* __restrict__ C, int M, int K, int Nt) {
  __shared__ __align__(16) u16 As[128 * 32];
  __shared__ __align__(16) u16 Bs[128 * 32];
  const int tid = threadIdx.x;
  const int bm0 = blockIdx.x * 128;
  const int bn0 = blockIdx.y * 128;
  const int wave = tid >> 6, lane = tid & 63;
  const int q = lane >> 4, r16 = lane & 15;
  const int wm = (wave >> 1) * 64, wn = (wave & 1) * 64;

  f32x4 acc[4][4];
#pragma unroll
  for (int i = 0; i < 4; i++)
#pragma unroll
    for (int j = 0; j < 4; j++) acc[i][j] = (f32x4){0.f, 0.f, 0.f, 0.f};

  // DMA mapping: linear chunk t = tid + 256*h -> LDS bytes [t*16, t*16+16)
  // = row t/4, col-chunk (t%4)*8. Global source = same row/chunk (row-major).
  const int r0 = tid >> 2;        // row for h=0 (0..63); h=1 adds 64
  const int c0 = (tid & 3) * 8;   // element offset of 16B chunk

  for (int kt = 0; kt < K; kt += 32) {
#pragma unroll
    for (int h = 0; h < 2; ++h) {
      int row = r0 + h * 64;
      // A rows may run past M for the last tile: stays inside d_ws (garbage ok,
      // masked at store). Bt rows always in range (Nt % 128 == 0).
      gload_lds16(A + (size_t)(bm0 + row) * K + kt + c0, &As[row * 32 + c0]);
      gload_lds16(Bt + (size_t)(bn0 + row) * K + kt + c0, &Bs[row * 32 + c0]);
    }
    __syncthreads();
    short8 af[4], bfr[4];
#pragma unroll
    for (int i = 0; i < 4; i++) af[i] = *(const short8*)(&As[(wm + i * 16 + r16) * 32 + q * 8]);
#pragma unroll
    for (int j = 0; j < 4; j++) bfr[j] = *(const short8*)(&Bs[(wn + j * 16 + r16) * 32 + q * 8]);
#pragma unroll
    for (int i = 0; i < 4; i++)
#pragma unroll
      for (int j = 0; j < 4; j++)
        acc[i][j] = __builtin_amdgcn_mfma_f32_16x16x32_bf16(af[i], bfr[j], acc[i][j], 0, 0, 0);
    __syncthreads();
  }

#pragma unroll
  for (int i = 0; i < 4; i++) {
#pragma unroll
    for (int r = 0; r < 4; r++) {
      int grow = bm0 + wm + i * 16 + q * 4 + r;  // C/D: row = quad*4 + reg
      if (grow >= M) continue;
      size_t rbase = (size_t)grow * Nt;
#pragma unroll
      for (int j = 0; j < 4; j++) {
        int gcol = bn0 + wn + j * 16 + r16;  // C/D: col = lane&15
        float v = acc[i][j][r] + bias[gcol];
        C[rbase + gcol] = f2bf(v);
      }
    }
  }
}

// ---------------- per-dst online-softmax aggregation ----------------
template <int VPL>
__device__ __forceinline__ void load_bf(const u16* __restrict__ p, int lane, float* f) {
  if constexpr (VPL == 4) {
    uint2 r = *(const uint2*)(p + lane * 4);
    f[0] = bf2f(r.x & 0xffffu); f[1] = bf2f(r.x >> 16);
    f[2] = bf2f(r.y & 0xffffu); f[3] = bf2f(r.y >> 16);
  } else {
    u32 r = *(const u32*)(p + lane * 2);
    f[0] = bf2f(r & 0xffffu); f[1] = bf2f(r >> 16);
  }
}

// one wave per dst node; 4-edge unroll for memory-level parallelism.
template <int H, bool OUT_BF16>
__global__ __launch_bounds__(256) void k_conv(
    const u16* __restrict__ qkvs, const int* __restrict__ offsets,
    const int* __restrict__ ssrc, u16* __restrict__ out_bf,
    float* __restrict__ out_f, int n, float scale) {
  constexpr int VPL = H / 64;
  int gw = (blockIdx.x * blockDim.x + threadIdx.x) >> 6;
  int lane = threadIdx.x & 63;
  if (gw >= n) return;
  const u16* base = qkvs + (size_t)gw * (4 * H);
  float qf[VPL];
  load_bf<VPL>(base, lane, qf);
  int beg = offsets[gw], end = offsets[gw + 1];
  float m = -INFINITY, l = 0.f;
  float agg[VPL];
#pragma unroll
  for (int w = 0; w < VPL; w++) agg[w] = 0.f;

  int i = beg;
  for (; i + 4 <= end; i += 4) {
    int s0 = ssrc[i], s1 = ssrc[i + 1], s2 = ssrc[i + 2], s3 = ssrc[i + 3];
    const u16* k0p = qkvs + (size_t)s0 * (4 * H) + H;
    const u16* k1p = qkvs + (size_t)s1 * (4 * H) + H;
    const u16* k2p = qkvs + (size_t)s2 * (4 * H) + H;
    const u16* k3p = qkvs + (size_t)s3 * (4 * H) + H;
    float k0[VPL], k1[VPL], k2[VPL], k3[VPL];
    float v0[VPL], v1[VPL], v2[VPL], v3[VPL];
    // all 8 gathers issued up front -> 8 loads in flight
    load_bf<VPL>(k0p, lane, k0);
    load_bf<VPL>(k1p, lane, k1);
    load_bf<VPL>(k2p, lane, k2);
    load_bf<VPL>(k3p, lane, k3);
    load_bf<VPL>(k0p + H, lane, v0);
    load_bf<VPL>(k1p + H, lane, v1);
    load_bf<VPL>(k2p + H, lane, v2);
    load_bf<VPL>(k3p + H, lane, v3);
    float d0 = 0.f, d1 = 0.f, d2 = 0.f, d3 = 0.f;
#pragma unroll
    for (int w = 0; w < VPL; w++) {
      d0 += qf[w] * k0[w]; d1 += qf[w] * k1[w];
      d2 += qf[w] * k2[w]; d3 += qf[w] * k3[w];
    }
#pragma unroll
    for (int off = 32; off > 0; off >>= 1) {  // 4 independent chains interleave
      d0 += __shfl_xor(d0, off, 64);
      d1 += __shfl_xor(d1, off, 64);
      d2 += __shfl_xor(d2, off, 64);
      d3 += __shfl_xor(d3, off, 64);
    }
    d0 *= scale; d1 *= scale; d2 *= scale; d3 *= scale;
    float cm = fmaxf(fmaxf(d0, d1), fmaxf(d2, d3));
    float nm = fmaxf(m, cm);
    float sc = __expf(m - nm);  // m=-inf first round -> 0
    float p0 = __expf(d0 - nm), p1 = __expf(d1 - nm);
    float p2 = __expf(d2 - nm), p3 = __expf(d3 - nm);
    m = nm;
    l = l * sc + (p0 + p1) + (p2 + p3);
#pragma unroll
    for (int w = 0; w < VPL; w++)
      agg[w] = agg[w] * sc + p0 * v0[w] + p1 * v1[w] + p2 * v2[w] + p3 * v3[w];
  }
  for (; i < end; ++i) {
    int s = ssrc[i];
    const u16* kb = qkvs + (size_t)s * (4 * H) + H;
    float kf[VPL], vf[VPL];
    load_bf<VPL>(kb, lane, kf);
    load_bf<VPL>(kb + H, lane, vf);
    float d = 0.f;
#pragma unroll
    for (int w = 0; w < VPL; w++) d += qf[w] * kf[w];
#pragma unroll
    for (int off = 32; off > 0; off >>= 1) d += __shfl_xor(d, off, 64);
    float score = d * scale;
    float nm = fmaxf(m, score);
    float sc = __expf(m - nm);
    float p = __expf(score - nm);
    m = nm;
    l = l * sc + p;
#pragma unroll
    for (int w = 0; w < VPL; w++) agg[w] = agg[w] * sc + p * vf[w];
  }

  float sf[VPL];
  load_bf<VPL>(base + 3 * H, lane, sf);
  float inv = (end > beg) ? 1.f / l : 0.f;
#pragma unroll
  for (int w = 0; w < VPL; w++) {
    float r = agg[w] * inv + sf[w];
    if (OUT_BF16) out_bf[(size_t)gw * H + lane * VPL + w] = f2bf(r);
    else out_f[(size_t)gw * H + lane * VPL + w] = r;
  }
}

// ---------------- graph layernorm (global mean/std) ----------------
__global__ void k_stats_bf16(const u16* __restrict__ a, int n, double* __restrict__ st) {
  float s = 0.f, s2 = 0.f;
  for (int i = blockIdx.x * blockDim.x + threadIdx.x; i < n; i += gridDim.x * blockDim.x) {
    float v = bf2f(a[i]);
    s += v; s2 += v * v;
  }
  __shared__ float sm[256], sm2[256];
  sm[threadIdx.x] = s; sm2[threadIdx.x] = s2;
  __syncthreads();
  for (int off = 128; off > 0; off >>= 1) {
    if (threadIdx.x < off) { sm[threadIdx.x] += sm[threadIdx.x + off]; sm2[threadIdx.x] += sm2[threadIdx.x + off]; }
    __syncthreads();
  }
  if (threadIdx.x == 0) { atomicAdd(&st[0], (double)sm[0]); atomicAdd(&st[1], (double)sm2[0]); }
}

__global__ void k_stats_f32(const float* __restrict__ a, int n, double* __restrict__ st) {
  float s = 0.f, s2 = 0.f;
  for (int i = blockIdx.x * blockDim.x + threadIdx.x; i < n; i += gridDim.x * blockDim.x) {
    float v = a[i];
    s += v; s2 += v * v;
  }
  __shared__ float sm[256], sm2[256];
  sm[threadIdx.x] = s; sm2[threadIdx.x] = s2;
  __syncthreads();
  for (int off = 128; off > 0; off >>= 1) {
    if (threadIdx.x < off) { sm[threadIdx.x] += sm[threadIdx.x + off]; sm2[threadIdx.x] += sm2[threadIdx.x + off]; }
    __syncthreads();
  }
  if (threadIdx.x == 0) { atomicAdd(&st[0], (double)sm[0]); atomicAdd(&st[1], (double)sm2[0]); }
}

__global__ void k_finstats(const double* __restrict__ st, float* __restrict__ fs, double cnt) {
  double mu = st[0] / cnt;
  double var = st[1] / cnt - mu * mu;
  if (var < 0.0) var = 0.0;
  fs[0] = (float)mu;
  fs[1] = (float)(1.0 / (sqrt(var) + (double)LN_EPS));
}

__global__ void k_norm_elu_bf16(const u16* __restrict__ a, const float* __restrict__ g,
                                const float* __restrict__ b, const float* __restrict__ fs,
                                u16* __restrict__ out, int n, int Hmask) {
  int i = blockIdx.x * blockDim.x + threadIdx.x;
  if (i >= n) return;
  int c = i & Hmask;
  float y = (bf2f(a[i]) - fs[0]) * fs[1] * g[c] + b[c];
  y = (y > 0.f) ? y : (__expf(y) - 1.f);  // ELU(alpha=1)
  out[i] = f2bf(y);
}

__global__ void k_norm_f32(float* __restrict__ a, const float* __restrict__ g,
                           const float* __restrict__ b, const float* __restrict__ fs,
                           int n, int Hmask) {
  int i = blockIdx.x * blockDim.x + threadIdx.x;
  if (i >= n) return;
  int c = i & Hmask;
  a[i] = (a[i] - fs[0]) * fs[1] * g[c] + b[c];
}

// ---------------- launch ----------------
extern "C" void kernel_launch(void* const* d_in, const int* in_sizes, int n_in,
                              void* d_out, int out_size, void* d_ws, size_t ws_size,
                              hipStream_t stream) {
  const float* x   = (const float*)d_in[0];
  const float* Wq1 = (const float*)d_in[1];  const float* bq1 = (const float*)d_in[2];
  const float* Wk1 = (const float*)d_in[3];  const float* bk1 = (const float*)d_in[4];
  const float* Wv1 = (const float*)d_in[5];  const float* bv1 = (const float*)d_in[6];
  const float* Ws1 = (const float*)d_in[7];  const float* bs1 = (const float*)d_in[8];
  const float* g1  = (const float*)d_in[9];  const float* be1 = (const float*)d_in[10];
  const float* Wq2 = (const float*)d_in[11]; const float* bq2 = (const float*)d_in[12];
  const float* Wk2 = (const float*)d_in[13]; const float* bk2 = (const float*)d_in[14];
  const float* Wv2 = (const float*)d_in[15]; const float* bv2 = (const float*)d_in[16];
  const float* Ws2 = (const float*)d_in[17]; const float* bs2 = (const float*)d_in[18];
  const float* g2  = (const float*)d_in[19]; const float* be2 = (const float*)d_in[20];
  const int*   ei  = (const int*)d_in[21];

  const int N = in_sizes[0] / IN_DIM;   // 50000
  const int E = in_sizes[21] / 2;       // 800000
  const int* esrc = ei;
  const int* edst = ei + E;

  // ---- workspace carve (256B aligned) ----
  char* w = (char*)d_ws;
  auto carve = [&](size_t bytes) { char* p = w; w += (bytes + 255) & ~(size_t)255; return p; };
  u16* x_bf  = (u16*)carve((size_t)N * IN_DIM * 2);          // later reused as h1
  u16* Wt1   = (u16*)carve((size_t)4 * HID * IN_DIM * 2);
  u16* Wt2   = (u16*)carve((size_t)4 * OUTD * HID * 2);
  float* bc1 = (float*)carve(4 * HID * 4);
  float* bc2 = (float*)carve(4 * OUTD * 4);
  u16* qkvs1 = (u16*)carve((size_t)N * 4 * HID * 2);         // later reused as qkvs2
  u16* a1    = (u16*)carve((size_t)N * HID * 2);
  int* deg   = (int*)carve((size_t)(N + 1) * 4);
  int* offs  = (int*)carve((size_t)(N + 1) * 4);
  int* cur   = (int*)carve((size_t)(N + 1) * 4);
  int* ssrc  = (int*)carve((size_t)E * 4);
  int* bsum  = (int*)carve(1024);
  int* boff  = (int*)carve(1024);
  double* st = (double*)carve(64);   // st[0..1]: layer1, st[2..3]: layer2
  float* fs  = (float*)carve(64);    // fs[0..1], fs[2..3]
  u16* h1    = x_bf;                 // x_bf dead after GEMM1
  u16* qkvs2 = qkvs1;                // qkvs1 dead after conv1

  hipMemsetAsync(deg, 0, (size_t)N * 4, stream);
  hipMemsetAsync(st, 0, 64, stream);

  // ---- prep ----
  int n4 = N * IN_DIM / 4;
  k_cvt_f32_bf16_v4<<<(n4 + 255) / 256, 256, 0, stream>>>(x, x_bf, n4);
  k_transpose_w<<<(IN_DIM * HID + 255) / 256, 256, 0, stream>>>(Wq1, Wt1 + 0 * (size_t)HID * IN_DIM, IN_DIM, HID);
  k_transpose_w<<<(IN_DIM * HID + 255) / 256, 256, 0, stream>>>(Wk1, Wt1 + 1 * (size_t)HID * IN_DIM, IN_DIM, HID);
  k_transpose_w<<<(IN_DIM * HID + 255) / 256, 256, 0, stream>>>(Wv1, Wt1 + 2 * (size_t)HID * IN_DIM, IN_DIM, HID);
  k_transpose_w<<<(IN_DIM * HID + 255) / 256, 256, 0, stream>>>(Ws1, Wt1 + 3 * (size_t)HID * IN_DIM, IN_DIM, HID);
  k_concat4<<<(4 * HID + 255) / 256, 256, 0, stream>>>(bq1, bk1, bv1, bs1, bc1, HID);
  k_transpose_w<<<(HID * OUTD + 255) / 256, 256, 0, stream>>>(Wq2, Wt2 + 0 * (size_t)OUTD * HID, HID, OUTD);
  k_transpose_w<<<(HID * OUTD + 255) / 256, 256, 0, stream>>>(Wk2, Wt2 + 1 * (size_t)OUTD * HID, HID, OUTD);
  k_transpose_w<<<(HID * OUTD + 255) / 256, 256, 0, stream>>>(Wv2, Wt2 + 2 * (size_t)OUTD * HID, HID, OUTD);
  k_transpose_w<<<(HID * OUTD + 255) / 256, 256, 0, stream>>>(Ws2, Wt2 + 3 * (size_t)OUTD * HID, HID, OUTD);
  k_concat4<<<(4 * OUTD + 255) / 256, 256, 0, stream>>>(bq2, bk2, bv2, bs2, bc2, OUTD);

  // ---- counting sort of edges by dst ----
  int nb = (N + 255) / 256;
  k_hist<<<(E + 255) / 256, 256, 0, stream>>>(edst, deg, E);
  k_block_sum<<<nb, 256, 0, stream>>>(deg, bsum, N);
  k_scan_bsum<<<1, 256, 0, stream>>>(bsum, boff, nb);
  k_scan_final<<<nb, 256, 0, stream>>>(deg, boff, offs, N, E);
  k_copy_int<<<nb, 256, 0, stream>>>(offs, cur, N);
  k_scatter<<<(E + 255) / 256, 256, 0, stream>>>(esrc, edst, cur, ssrc, E);

  // ---- layer 1 ----
  dim3 gg1((N + 127) / 128, (4 * HID) / 128);
  k_gemm_bf16_nt<<<gg1, 256, 0, stream>>>(x_bf, Wt1, bc1, qkvs1, N, IN_DIM, 4 * HID);
  k_conv<HID, true><<<(N + 3) / 4, 256, 0, stream>>>(qkvs1, offs, ssrc, a1, nullptr, N,
                                                     1.0f / sqrtf((float)HID));
  k_stats_bf16<<<2048, 256, 0, stream>>>(a1, N * HID, st);
  k_finstats<<<1, 1, 0, stream>>>(st, fs, (double)N * HID);
  k_norm_elu_bf16<<<(N * HID + 255) / 256, 256, 0, stream>>>(a1, g1, be1, fs, h1, N * HID, HID - 1);

  // ---- layer 2 ----
  dim3 gg2((N + 127) / 128, (4 * OUTD) / 128);
  k_gemm_bf16_nt<<<gg2, 256, 0, stream>>>(h1, Wt2, bc2, qkvs2, N, HID, 4 * OUTD);
  k_conv<OUTD, false><<<(N + 3) / 4, 256, 0, stream>>>(qkvs2, offs, ssrc, nullptr, (float*)d_out, N,
                                                       1.0f / sqrtf((float)OUTD));
  k_stats_f32<<<2048, 256, 0, stream>>>((const float*)d_out, N * OUTD, st + 2);
  k_finstats<<<1, 1, 0, stream>>>(st + 2, fs + 2, (double)N * OUTD);
  k_norm_f32<<<(N * OUTD + 255) / 256, 256, 0, stream>>>((float*)d_out, g2, be2, fs + 2, N * OUTD, OUTD - 1);
}